// Round 9
// baseline (494.513 us; speedup 1.0000x reference)
//
#include <hip/hip_runtime.h>
#include <hip/hip_bf16.h>
#include <hip/hip_fp16.h>

#define NB 16
#define MB 20000
#define FINC 64
#define FOUTC 64
#define KCH 6
#define NNZC 160000
#define CW 1024  /* FIN*N columns per term row */
#define ELLW 32  /* ELL width; Poisson(8) => P(deg>32) ~ 1e-12 */

typedef __attribute__((ext_vector_type(8))) short short8;
typedef __attribute__((ext_vector_type(4))) float float4v;
typedef __attribute__((ext_vector_type(4))) unsigned int ui4;

__device__ inline unsigned short f2bf(float f){
  unsigned int u = __float_as_uint(f);
  u += 0x7FFFu + ((u >> 16) & 1u);   // round-to-nearest-even
  return (unsigned short)(u >> 16);
}
__device__ inline float bflo(unsigned int u){ return __uint_as_float(u << 16); }
__device__ inline float bfhi(unsigned int u){ return __uint_as_float(u & 0xFFFF0000u); }
__device__ inline float h2f(unsigned int bits){
  __half_raw hr; hr.x = (unsigned short)bits;
  return __half2float(*(__half*)&hr);
}

// ---- ELL build: packed 4B entries (col:u16 | f16(val)<<16). ----
__global__ void k_build(const int* __restrict__ rows, const int* __restrict__ cols,
                        const float* __restrict__ vals,
                        int* __restrict__ cnt, unsigned int* __restrict__ ell){
  int i = blockIdx.x * 256 + threadIdx.x;
  if (i < NNZC){
    int r = rows[i];
    int slot = atomicAdd(&cnt[r], 1);
    if (slot < ELLW){
      __half h = __float2half(vals[i]);
      __half_raw hr = *(__half_raw*)&h;
      unsigned int entry = (unsigned int)(unsigned short)cols[i] | ((unsigned int)hr.x << 16);
      ell[r * ELLW + slot] = entry;
    }
  }
}

// ---- fused: transpose x[n][m][f] -> G0[m][n*64+f] (bf16)  +  weight permute ----
__global__ void __launch_bounds__(256) k_prep(const float* __restrict__ x,
                                              const float* __restrict__ w,
                                              unsigned short* __restrict__ G0,
                                              unsigned short* __restrict__ W2t){
  int b = blockIdx.x;
  if (b < 1250){
    int t = threadIdx.x;
    int m = b * 16 + (t >> 4);
    int fc = (t & 15) * 4;
    #pragma unroll
    for (int n = 0; n < NB; n++){
      float4 a = *(const float4*)(x + ((size_t)n * MB + m) * FINC + fc);
      unsigned short tmp[4] = {f2bf(a.x), f2bf(a.y), f2bf(a.z), f2bf(a.w)};
      *(uint2*)(G0 + (size_t)m * CW + n * FINC + fc) = *(const uint2*)tmp;
    }
  } else {
    // W2t[k][fo][f] = bf16(weight[f*6+k][fo])
    int idx = (b - 1250) * 256 + threadIdx.x;
    if (idx < KCH * FINC * FOUTC){
      int k  = idx / (FINC * FOUTC);
      int fo = (idx / FINC) % FOUTC;
      int f  = idx % FINC;
      W2t[idx] = f2bf(w[(f * KCH + k) * FOUTC + fo]);
    }
  }
}

// ---- SpMM + Chebyshev recurrence, sequential column-slab form ----
// EXACT R5 config (399.2 us). Parked: gathers are MSHR-capped at LLC
// latency; MLP-deepening (R5/R6) and cache hints (R2/R7) all null.
__device__ inline void gacc(float* acc, ui4 raw, float v){
  acc[0] += v * bflo(raw.x); acc[1] += v * bfhi(raw.x);
  acc[2] += v * bflo(raw.y); acc[3] += v * bfhi(raw.y);
  acc[4] += v * bflo(raw.z); acc[5] += v * bfhi(raw.z);
  acc[6] += v * bflo(raw.w); acc[7] += v * bfhi(raw.w);
}

__global__ void __launch_bounds__(128) k_spmm(const unsigned short* __restrict__ Gin,
                                              const unsigned short* __restrict__ Gprev,
                                              unsigned short* __restrict__ Gout,
                                              const int* __restrict__ cnt,
                                              const unsigned int* __restrict__ ell,
                                              int first){
  int bid = blockIdx.x;
  int xcd   = bid & 7;
  int t2    = bid >> 3;           // 0..2499
  int phase = t2 / 1250;          // 0 or 1: which of this XCD's two slabs
  int mg    = t2 - phase * 1250;  // 0..1249
  int slab  = xcd + 8 * phase;
  int t = threadIdx.x;
  int m = mg * 16 + (t >> 3);
  int co = slab * 64 + (t & 7) * 8;
  int deg = cnt[m]; if (deg > ELLW) deg = ELLW;

  const ui4* ep4 = (const ui4*)(ell + m * ELLW);   // 4 packed entries per ui4
  // batch-load leading 8 ELL entries (always valid: table zero-padded;
  // pad slots gather row 0 with v=0 -> hot line, harmless)
  ui4 q0 = ep4[0];
  ui4 q1 = ep4[1];
  // prefetch Gprev early (normal cached load, overlaps with gathers)
  ui4 pr = (ui4){0u,0u,0u,0u};
  if (!first) pr = *(const ui4*)(Gprev + (size_t)m * CW + co);

  const unsigned short* gb = Gin + co;
  // issue all 8 gathers before any FMA: 8-deep MLP
  ui4 r0 = *(const ui4*)(gb + (size_t)(q0.x & 0xFFFFu) * CW);
  ui4 r1 = *(const ui4*)(gb + (size_t)(q0.y & 0xFFFFu) * CW);
  ui4 r2 = *(const ui4*)(gb + (size_t)(q0.z & 0xFFFFu) * CW);
  ui4 r3 = *(const ui4*)(gb + (size_t)(q0.w & 0xFFFFu) * CW);
  ui4 r4 = *(const ui4*)(gb + (size_t)(q1.x & 0xFFFFu) * CW);
  ui4 r5 = *(const ui4*)(gb + (size_t)(q1.y & 0xFFFFu) * CW);
  ui4 r6 = *(const ui4*)(gb + (size_t)(q1.z & 0xFFFFu) * CW);
  ui4 r7 = *(const ui4*)(gb + (size_t)(q1.w & 0xFFFFu) * CW);

  float acc[8] = {0.f,0.f,0.f,0.f,0.f,0.f,0.f,0.f};
  gacc(acc, r0, h2f(q0.x >> 16));
  gacc(acc, r1, h2f(q0.y >> 16));
  gacc(acc, r2, h2f(q0.z >> 16));
  gacc(acc, r3, h2f(q0.w >> 16));
  gacc(acc, r4, h2f(q1.x >> 16));
  gacc(acc, r5, h2f(q1.y >> 16));
  gacc(acc, r6, h2f(q1.z >> 16));
  gacc(acc, r7, h2f(q1.w >> 16));

  if (deg > 8){                   // Poisson(8): ~41% of rows, EXEC-masked
    for (int e = 8; e < deg; e += 8){
      ui4 a0 = ep4[e >> 2];
      ui4 a1 = ep4[(e >> 2) + 1];
      ui4 s0 = *(const ui4*)(gb + (size_t)(a0.x & 0xFFFFu) * CW);
      ui4 s1 = *(const ui4*)(gb + (size_t)(a0.y & 0xFFFFu) * CW);
      ui4 s2 = *(const ui4*)(gb + (size_t)(a0.z & 0xFFFFu) * CW);
      ui4 s3 = *(const ui4*)(gb + (size_t)(a0.w & 0xFFFFu) * CW);
      ui4 s4 = *(const ui4*)(gb + (size_t)(a1.x & 0xFFFFu) * CW);
      ui4 s5 = *(const ui4*)(gb + (size_t)(a1.y & 0xFFFFu) * CW);
      ui4 s6 = *(const ui4*)(gb + (size_t)(a1.z & 0xFFFFu) * CW);
      ui4 s7 = *(const ui4*)(gb + (size_t)(a1.w & 0xFFFFu) * CW);
      gacc(acc, s0, h2f(a0.x >> 16));
      gacc(acc, s1, h2f(a0.y >> 16));
      gacc(acc, s2, h2f(a0.z >> 16));
      gacc(acc, s3, h2f(a0.w >> 16));
      gacc(acc, s4, h2f(a1.x >> 16));
      gacc(acc, s5, h2f(a1.y >> 16));
      gacc(acc, s6, h2f(a1.z >> 16));
      gacc(acc, s7, h2f(a1.w >> 16));
    }
  }

  if (!first){
    float pv[8] = {bflo(pr.x), bfhi(pr.x), bflo(pr.y), bfhi(pr.y),
                   bflo(pr.z), bfhi(pr.z), bflo(pr.w), bfhi(pr.w)};
    #pragma unroll
    for (int i = 0; i < 8; i++) acc[i] = 2.f * acc[i] - pv[i];
  }
  unsigned short o[8];
  #pragma unroll
  for (int i = 0; i < 8; i++) o[i] = f2bf(acc[i]);
  *(ui4*)(Gout + (size_t)m * CW + co) = *(const ui4*)o;
}

// ---- GEMM: out[n][m][fo] = bias[fo] + sum_{k,f} G_k[m][n*64+f] * W2t[k][fo][f] ----
// R9: R8's T14 schedule was right, the ALLOCATION was wrong: VGPR stayed
// 52 and the 6xuint4 prefetch spilled to scratch (WRITE_SIZE 80->375 MB).
// __launch_bounds__(256, 2): min 2 waves/EU -> VGPR cap 256/wave -> the
// prefetch lives in registers. Occupancy 2.4 -> 2 blocks/CU (ILP replaces
// TLP). Check: VGPR ~80-110, WRITE back to 80 MB, FETCH 120 MB.
#define LDA 72   /* 64 + 8 pad elems: breaks 16-way LDS bank conflict on b128 reads */
__global__ void __launch_bounds__(256, 2) k_gemm(const unsigned short* __restrict__ G,
                                                 const unsigned short* __restrict__ W2t,
                                                 const float* __restrict__ bias,
                                                 float* __restrict__ out){
  __shared__ unsigned short la[128 * LDA];   // 18432 B: A-slab (128 rows x 64 k)
  __shared__ unsigned short lb[FOUTC * LDA]; // 9216 B: B-slab (64 fo x 64 f, transposed)
  int tid  = threadIdx.x;
  int wave = tid >> 6, lane = tid & 63;
  int quad = lane >> 4, l16 = lane & 15;
  int mblk = blockIdx.x;           // 8 m-rows = 128 GEMM rows per block
  const size_t gsz = (size_t)MB * CW;

  float4v acc[2][4];
  #pragma unroll
  for (int i = 0; i < 2; i++)
    #pragma unroll
    for (int j = 0; j < 4; j++) acc[i][j] = (float4v){0.f, 0.f, 0.f, 0.f};

  // prologue: k=0 A/B slabs -> registers
  uint4 ra[4]; uint4 rb[2];
  {
    const unsigned short* a0 = G + (size_t)mblk * 8 * CW;
    #pragma unroll
    for (int it = 0; it < 4; it++) ra[it] = *(const uint4*)(a0 + (it * 256 + tid) * 8);
    #pragma unroll
    for (int it = 0; it < 2; it++) rb[it] = *(const uint4*)(W2t + (it * 256 + tid) * 8);
  }

  for (int k = 0; k < KCH; k++){
    __syncthreads();  // previous iteration's frag reads done before overwrite
    #pragma unroll
    for (int it = 0; it < 4; it++){
      int e0 = (it * 256 + tid) * 8;
      *(uint4*)(&la[(e0 >> 6) * LDA + (e0 & 63)]) = ra[it];
    }
    #pragma unroll
    for (int it = 0; it < 2; it++){
      int e0 = (it * 256 + tid) * 8;
      *(uint4*)(&lb[(e0 >> 6) * LDA + (e0 & 63)]) = rb[it];
    }
    __syncthreads();
    // issue k+1 loads NOW: in flight across frag reads + MFMAs + barriers
    if (k + 1 < KCH){
      const unsigned short* an = G + (size_t)(k + 1) * gsz + (size_t)mblk * 8 * CW;
      const unsigned short* bn = W2t + (k + 1) * (FINC * FOUTC);
      #pragma unroll
      for (int it = 0; it < 4; it++) ra[it] = *(const uint4*)(an + (it * 256 + tid) * 8);
      #pragma unroll
      for (int it = 0; it < 2; it++) rb[it] = *(const uint4*)(bn + (it * 256 + tid) * 8);
    }
    #pragma unroll
    for (int kc = 0; kc < 2; kc++){
      short8 af[2], bfr[4];
      #pragma unroll
      for (int rt = 0; rt < 2; rt++){
        int row = wave * 32 + rt * 16 + l16;
        af[rt] = *(const short8*)(&la[row * LDA + kc * 32 + quad * 8]);
      }
      #pragma unroll
      for (int ct = 0; ct < 4; ct++){
        int fo = ct * 16 + l16;
        bfr[ct] = *(const short8*)(&lb[fo * LDA + kc * 32 + quad * 8]);
      }
      #pragma unroll
      for (int rt = 0; rt < 2; rt++)
        #pragma unroll
        for (int ct = 0; ct < 4; ct++)
          acc[rt][ct] = __builtin_amdgcn_mfma_f32_16x16x32_bf16(af[rt], bfr[ct], acc[rt][ct], 0, 0, 0);
    }
  }
  // epilogue: C/D layout col=lane&15, row=quad*4+reg
  #pragma unroll
  for (int ct = 0; ct < 4; ct++){
    int fo = ct * 16 + l16;
    float bv = bias[fo];
    #pragma unroll
    for (int rt = 0; rt < 2; rt++){
      #pragma unroll
      for (int reg = 0; reg < 4; reg++){
        int rloc = wave * 32 + rt * 16 + quad * 4 + reg;
        int r = mblk * 128 + rloc;
        int m = r >> 4, n = r & 15;
        out[((size_t)n * MB + m) * FOUTC + fo] = acc[rt][ct][reg] + bv;
      }
    }
  }
}

extern "C" void kernel_launch(void* const* d_in, const int* in_sizes, int n_in,
                              void* d_out, int out_size, void* d_ws, size_t ws_size,
                              hipStream_t stream){
  const float* x    = (const float*)d_in[0];
  const float* Lv   = (const float*)d_in[1];
  const float* w    = (const float*)d_in[2];
  const float* bias = (const float*)d_in[3];
  const int*   Lr   = (const int*)d_in[4];
  const int*   Lc   = (const int*)d_in[5];
  float* out = (float*)d_out;

  char* ws = (char*)d_ws;
  // ws layout: G[6] terms (245,760,000 B) | W2t (49,152) | cnt (80,000)
  unsigned short* G   = (unsigned short*)ws;
  unsigned short* W2t = (unsigned short*)(ws + 245760000);
  int* cnt            = (int*)(ws + 245809152);
  // ELL edge table lives in d_out (2.56 MB packed; gemm fully overwrites
  // d_out afterwards, nothing reads ell past the last spmm).
  unsigned int* ell = (unsigned int*)d_out;

  (void)hipMemsetAsync(cnt, 0, MB * sizeof(int), stream);
  (void)hipMemsetAsync(ell, 0, MB * ELLW * sizeof(unsigned int), stream);  // zero-pad slots

  k_build<<<dim3((NNZC + 255) / 256), dim3(256), 0, stream>>>(Lr, Lc, Lv, cnt, ell);
  k_prep <<<dim3(1250 + 96), dim3(256), 0, stream>>>(x, w, G, W2t);

  const size_t gsz = (size_t)MB * CW;
  k_spmm<<<dim3(1250 * 16), dim3(128), 0, stream>>>(G, (const unsigned short*)nullptr, G + gsz,
                                                    cnt, ell, 1);
  for (int k = 2; k < KCH; k++)
    k_spmm<<<dim3(1250 * 16), dim3(128), 0, stream>>>(G + (size_t)(k - 1) * gsz, G + (size_t)(k - 2) * gsz,
                                                      G + (size_t)k * gsz, cnt, ell, 0);

  k_gemm<<<dim3(MB / 8), dim3(256), 0, stream>>>(G, W2t, bias, out);
}

// Round 10
// 397.261 us; speedup vs baseline: 1.2448x; 1.2448x over previous
//
#include <hip/hip_runtime.h>
#include <hip/hip_bf16.h>
#include <hip/hip_fp16.h>

#define NB 16
#define MB 20000
#define FINC 64
#define FOUTC 64
#define KCH 6
#define NNZC 160000
#define CW 1024  /* FIN*N columns per term row */
#define ELLW 32  /* ELL width; Poisson(8) => P(deg>32) ~ 1e-12 */

typedef __attribute__((ext_vector_type(8))) short short8;
typedef __attribute__((ext_vector_type(4))) float float4v;
typedef __attribute__((ext_vector_type(4))) unsigned int ui4;

__device__ inline unsigned short f2bf(float f){
  unsigned int u = __float_as_uint(f);
  u += 0x7FFFu + ((u >> 16) & 1u);   // round-to-nearest-even
  return (unsigned short)(u >> 16);
}
__device__ inline float bflo(unsigned int u){ return __uint_as_float(u << 16); }
__device__ inline float bfhi(unsigned int u){ return __uint_as_float(u & 0xFFFF0000u); }
__device__ inline float h2f(unsigned int bits){
  __half_raw hr; hr.x = (unsigned short)bits;
  return __half2float(*(__half*)&hr);
}

// ---- ELL build: packed 4B entries (col:u16 | f16(val)<<16). ----
__global__ void k_build(const int* __restrict__ rows, const int* __restrict__ cols,
                        const float* __restrict__ vals,
                        int* __restrict__ cnt, unsigned int* __restrict__ ell){
  int i = blockIdx.x * 256 + threadIdx.x;
  if (i < NNZC){
    int r = rows[i];
    int slot = atomicAdd(&cnt[r], 1);
    if (slot < ELLW){
      __half h = __float2half(vals[i]);
      __half_raw hr = *(__half_raw*)&h;
      unsigned int entry = (unsigned int)(unsigned short)cols[i] | ((unsigned int)hr.x << 16);
      ell[r * ELLW + slot] = entry;
    }
  }
}

// ---- fused: transpose x[n][m][f] -> G0[m][n*64+f] (bf16)  +  weight permute ----
__global__ void __launch_bounds__(256) k_prep(const float* __restrict__ x,
                                              const float* __restrict__ w,
                                              unsigned short* __restrict__ G0,
                                              unsigned short* __restrict__ W2t){
  int b = blockIdx.x;
  if (b < 1250){
    int t = threadIdx.x;
    int m = b * 16 + (t >> 4);
    int fc = (t & 15) * 4;
    #pragma unroll
    for (int n = 0; n < NB; n++){
      float4 a = *(const float4*)(x + ((size_t)n * MB + m) * FINC + fc);
      unsigned short tmp[4] = {f2bf(a.x), f2bf(a.y), f2bf(a.z), f2bf(a.w)};
      *(uint2*)(G0 + (size_t)m * CW + n * FINC + fc) = *(const uint2*)tmp;
    }
  } else {
    // W2t[k][fo][f] = bf16(weight[f*6+k][fo])
    int idx = (b - 1250) * 256 + threadIdx.x;
    if (idx < KCH * FINC * FOUTC){
      int k  = idx / (FINC * FOUTC);
      int fo = (idx / FINC) % FOUTC;
      int f  = idx % FINC;
      W2t[idx] = f2bf(w[(f * KCH + k) * FOUTC + fo]);
    }
  }
}

// ---- SpMM + Chebyshev recurrence, sequential column-slab form ----
// EXACT R5 config (399.2 us). Parked: gathers are MSHR-capped at LLC
// latency; MLP-deepening (R5/R6) and cache hints (R2/R7) all null.
__device__ inline void gacc(float* acc, ui4 raw, float v){
  acc[0] += v * bflo(raw.x); acc[1] += v * bfhi(raw.x);
  acc[2] += v * bflo(raw.y); acc[3] += v * bfhi(raw.y);
  acc[4] += v * bflo(raw.z); acc[5] += v * bfhi(raw.z);
  acc[6] += v * bflo(raw.w); acc[7] += v * bfhi(raw.w);
}

__global__ void __launch_bounds__(128) k_spmm(const unsigned short* __restrict__ Gin,
                                              const unsigned short* __restrict__ Gprev,
                                              unsigned short* __restrict__ Gout,
                                              const int* __restrict__ cnt,
                                              const unsigned int* __restrict__ ell,
                                              int first){
  int bid = blockIdx.x;
  int xcd   = bid & 7;
  int t2    = bid >> 3;           // 0..2499
  int phase = t2 / 1250;          // 0 or 1: which of this XCD's two slabs
  int mg    = t2 - phase * 1250;  // 0..1249
  int slab  = xcd + 8 * phase;
  int t = threadIdx.x;
  int m = mg * 16 + (t >> 3);
  int co = slab * 64 + (t & 7) * 8;
  int deg = cnt[m]; if (deg > ELLW) deg = ELLW;

  const ui4* ep4 = (const ui4*)(ell + m * ELLW);   // 4 packed entries per ui4
  // batch-load leading 8 ELL entries (always valid: table zero-padded;
  // pad slots gather row 0 with v=0 -> hot line, harmless)
  ui4 q0 = ep4[0];
  ui4 q1 = ep4[1];
  // prefetch Gprev early (normal cached load, overlaps with gathers)
  ui4 pr = (ui4){0u,0u,0u,0u};
  if (!first) pr = *(const ui4*)(Gprev + (size_t)m * CW + co);

  const unsigned short* gb = Gin + co;
  // issue all 8 gathers before any FMA: 8-deep MLP
  ui4 r0 = *(const ui4*)(gb + (size_t)(q0.x & 0xFFFFu) * CW);
  ui4 r1 = *(const ui4*)(gb + (size_t)(q0.y & 0xFFFFu) * CW);
  ui4 r2 = *(const ui4*)(gb + (size_t)(q0.z & 0xFFFFu) * CW);
  ui4 r3 = *(const ui4*)(gb + (size_t)(q0.w & 0xFFFFu) * CW);
  ui4 r4 = *(const ui4*)(gb + (size_t)(q1.x & 0xFFFFu) * CW);
  ui4 r5 = *(const ui4*)(gb + (size_t)(q1.y & 0xFFFFu) * CW);
  ui4 r6 = *(const ui4*)(gb + (size_t)(q1.z & 0xFFFFu) * CW);
  ui4 r7 = *(const ui4*)(gb + (size_t)(q1.w & 0xFFFFu) * CW);

  float acc[8] = {0.f,0.f,0.f,0.f,0.f,0.f,0.f,0.f};
  gacc(acc, r0, h2f(q0.x >> 16));
  gacc(acc, r1, h2f(q0.y >> 16));
  gacc(acc, r2, h2f(q0.z >> 16));
  gacc(acc, r3, h2f(q0.w >> 16));
  gacc(acc, r4, h2f(q1.x >> 16));
  gacc(acc, r5, h2f(q1.y >> 16));
  gacc(acc, r6, h2f(q1.z >> 16));
  gacc(acc, r7, h2f(q1.w >> 16));

  if (deg > 8){                   // Poisson(8): ~41% of rows, EXEC-masked
    for (int e = 8; e < deg; e += 8){
      ui4 a0 = ep4[e >> 2];
      ui4 a1 = ep4[(e >> 2) + 1];
      ui4 s0 = *(const ui4*)(gb + (size_t)(a0.x & 0xFFFFu) * CW);
      ui4 s1 = *(const ui4*)(gb + (size_t)(a0.y & 0xFFFFu) * CW);
      ui4 s2 = *(const ui4*)(gb + (size_t)(a0.z & 0xFFFFu) * CW);
      ui4 s3 = *(const ui4*)(gb + (size_t)(a0.w & 0xFFFFu) * CW);
      ui4 s4 = *(const ui4*)(gb + (size_t)(a1.x & 0xFFFFu) * CW);
      ui4 s5 = *(const ui4*)(gb + (size_t)(a1.y & 0xFFFFu) * CW);
      ui4 s6 = *(const ui4*)(gb + (size_t)(a1.z & 0xFFFFu) * CW);
      ui4 s7 = *(const ui4*)(gb + (size_t)(a1.w & 0xFFFFu) * CW);
      gacc(acc, s0, h2f(a0.x >> 16));
      gacc(acc, s1, h2f(a0.y >> 16));
      gacc(acc, s2, h2f(a0.z >> 16));
      gacc(acc, s3, h2f(a0.w >> 16));
      gacc(acc, s4, h2f(a1.x >> 16));
      gacc(acc, s5, h2f(a1.y >> 16));
      gacc(acc, s6, h2f(a1.z >> 16));
      gacc(acc, s7, h2f(a1.w >> 16));
    }
  }

  if (!first){
    float pv[8] = {bflo(pr.x), bfhi(pr.x), bflo(pr.y), bfhi(pr.y),
                   bflo(pr.z), bfhi(pr.z), bflo(pr.w), bfhi(pr.w)};
    #pragma unroll
    for (int i = 0; i < 8; i++) acc[i] = 2.f * acc[i] - pv[i];
  }
  unsigned short o[8];
  #pragma unroll
  for (int i = 0; i < 8; i++) o[i] = f2bf(acc[i]);
  *(ui4*)(Gout + (size_t)m * CW + co) = *(const ui4*)o;
}

// ---- GEMM: out[n][m][fo] = bias[fo] + sum_{k,f} G_k[m][n*64+f] * W2t[k][fo][f] ----
// R10: R8/R9 spill root-caused as FAILED SROA (rule #20 variant): uint4
// ARRAYS with conditional, loop-carried assignment across barriers stay
// in a scratch alloca (VGPR 48-52, WRITE +295 MB = scratch traffic).
// Fix: NAMED SCALARS ra0..ra3/rb0..rb1 (pure SSA) + UNCONDITIONAL
// prefetch (kn = min(k+1, KCH-1); last iter re-reads k=5 from L2,
// harmless). Check: VGPR ~90-110, WRITE 80 MB, FETCH 120 MB.
#define LDA 72   /* 64 + 8 pad elems: breaks 16-way LDS bank conflict on b128 reads */
__global__ void __launch_bounds__(256, 2) k_gemm(const unsigned short* __restrict__ G,
                                                 const unsigned short* __restrict__ W2t,
                                                 const float* __restrict__ bias,
                                                 float* __restrict__ out){
  __shared__ unsigned short la[128 * LDA];   // 18432 B: A-slab (128 rows x 64 k)
  __shared__ unsigned short lb[FOUTC * LDA]; // 9216 B: B-slab (64 fo x 64 f, transposed)
  int tid  = threadIdx.x;
  int wave = tid >> 6, lane = tid & 63;
  int quad = lane >> 4, l16 = lane & 15;
  int mblk = blockIdx.x;           // 8 m-rows = 128 GEMM rows per block
  const size_t gsz = (size_t)MB * CW;

  float4v acc[2][4];
  #pragma unroll
  for (int i = 0; i < 2; i++)
    #pragma unroll
    for (int j = 0; j < 4; j++) acc[i][j] = (float4v){0.f, 0.f, 0.f, 0.f};

  // prologue: k=0 A/B slabs -> named scalar registers (SSA, no alloca)
  const unsigned short* a0p = G + (size_t)mblk * 8 * CW;
  uint4 ra0 = *(const uint4*)(a0p + (0 * 256 + tid) * 8);
  uint4 ra1 = *(const uint4*)(a0p + (1 * 256 + tid) * 8);
  uint4 ra2 = *(const uint4*)(a0p + (2 * 256 + tid) * 8);
  uint4 ra3 = *(const uint4*)(a0p + (3 * 256 + tid) * 8);
  uint4 rb0 = *(const uint4*)(W2t + (0 * 256 + tid) * 8);
  uint4 rb1 = *(const uint4*)(W2t + (1 * 256 + tid) * 8);

  for (int k = 0; k < KCH; k++){
    __syncthreads();  // previous iteration's frag reads done before overwrite
    {
      int e0;
      e0 = (0 * 256 + tid) * 8; *(uint4*)(&la[(e0 >> 6) * LDA + (e0 & 63)]) = ra0;
      e0 = (1 * 256 + tid) * 8; *(uint4*)(&la[(e0 >> 6) * LDA + (e0 & 63)]) = ra1;
      e0 = (2 * 256 + tid) * 8; *(uint4*)(&la[(e0 >> 6) * LDA + (e0 & 63)]) = ra2;
      e0 = (3 * 256 + tid) * 8; *(uint4*)(&la[(e0 >> 6) * LDA + (e0 & 63)]) = ra3;
      e0 = (0 * 256 + tid) * 8; *(uint4*)(&lb[(e0 >> 6) * LDA + (e0 & 63)]) = rb0;
      e0 = (1 * 256 + tid) * 8; *(uint4*)(&lb[(e0 >> 6) * LDA + (e0 & 63)]) = rb1;
    }
    __syncthreads();
    // unconditional next-tile prefetch: in flight across frag reads +
    // 16 MFMAs + both barriers (last iter re-reads k=5: L2-hit, harmless)
    int kn = (k + 1 < KCH) ? k + 1 : k;
    const unsigned short* an = G + (size_t)kn * gsz + (size_t)mblk * 8 * CW;
    const unsigned short* bn = W2t + kn * (FINC * FOUTC);
    uint4 na0 = *(const uint4*)(an + (0 * 256 + tid) * 8);
    uint4 na1 = *(const uint4*)(an + (1 * 256 + tid) * 8);
    uint4 na2 = *(const uint4*)(an + (2 * 256 + tid) * 8);
    uint4 na3 = *(const uint4*)(an + (3 * 256 + tid) * 8);
    uint4 nb0 = *(const uint4*)(bn + (0 * 256 + tid) * 8);
    uint4 nb1 = *(const uint4*)(bn + (1 * 256 + tid) * 8);

    #pragma unroll
    for (int kc = 0; kc < 2; kc++){
      short8 af[2], bfr[4];
      #pragma unroll
      for (int rt = 0; rt < 2; rt++){
        int row = wave * 32 + rt * 16 + l16;
        af[rt] = *(const short8*)(&la[row * LDA + kc * 32 + quad * 8]);
      }
      #pragma unroll
      for (int ct = 0; ct < 4; ct++){
        int fo = ct * 16 + l16;
        bfr[ct] = *(const short8*)(&lb[fo * LDA + kc * 32 + quad * 8]);
      }
      #pragma unroll
      for (int rt = 0; rt < 2; rt++)
        #pragma unroll
        for (int ct = 0; ct < 4; ct++)
          acc[rt][ct] = __builtin_amdgcn_mfma_f32_16x16x32_bf16(af[rt], bfr[ct], acc[rt][ct], 0, 0, 0);
    }
    ra0 = na0; ra1 = na1; ra2 = na2; ra3 = na3; rb0 = nb0; rb1 = nb1;
  }
  // epilogue: C/D layout col=lane&15, row=quad*4+reg
  #pragma unroll
  for (int ct = 0; ct < 4; ct++){
    int fo = ct * 16 + l16;
    float bv = bias[fo];
    #pragma unroll
    for (int rt = 0; rt < 2; rt++){
      #pragma unroll
      for (int reg = 0; reg < 4; reg++){
        int rloc = wave * 32 + rt * 16 + quad * 4 + reg;
        int r = mblk * 128 + rloc;
        int m = r >> 4, n = r & 15;
        out[((size_t)n * MB + m) * FOUTC + fo] = acc[rt][ct][reg] + bv;
      }
    }
  }
}

extern "C" void kernel_launch(void* const* d_in, const int* in_sizes, int n_in,
                              void* d_out, int out_size, void* d_ws, size_t ws_size,
                              hipStream_t stream){
  const float* x    = (const float*)d_in[0];
  const float* Lv   = (const float*)d_in[1];
  const float* w    = (const float*)d_in[2];
  const float* bias = (const float*)d_in[3];
  const int*   Lr   = (const int*)d_in[4];
  const int*   Lc   = (const int*)d_in[5];
  float* out = (float*)d_out;

  char* ws = (char*)d_ws;
  // ws layout: G[6] terms (245,760,000 B) | W2t (49,152) | cnt (80,000)
  unsigned short* G   = (unsigned short*)ws;
  unsigned short* W2t = (unsigned short*)(ws + 245760000);
  int* cnt            = (int*)(ws + 245809152);
  // ELL edge table lives in d_out (2.56 MB packed; gemm fully overwrites
  // d_out afterwards, nothing reads ell past the last spmm).
  unsigned int* ell = (unsigned int*)d_out;

  (void)hipMemsetAsync(cnt, 0, MB * sizeof(int), stream);
  (void)hipMemsetAsync(ell, 0, MB * ELLW * sizeof(unsigned int), stream);  // zero-pad slots

  k_build<<<dim3((NNZC + 255) / 256), dim3(256), 0, stream>>>(Lr, Lc, Lv, cnt, ell);
  k_prep <<<dim3(1250 + 96), dim3(256), 0, stream>>>(x, w, G, W2t);

  const size_t gsz = (size_t)MB * CW;
  k_spmm<<<dim3(1250 * 16), dim3(128), 0, stream>>>(G, (const unsigned short*)nullptr, G + gsz,
                                                    cnt, ell, 1);
  for (int k = 2; k < KCH; k++)
    k_spmm<<<dim3(1250 * 16), dim3(128), 0, stream>>>(G + (size_t)(k - 1) * gsz, G + (size_t)(k - 2) * gsz,
                                                      G + (size_t)k * gsz, cnt, ell, 0);

  k_gemm<<<dim3(MB / 8), dim3(256), 0, stream>>>(G, W2t, bias, out);
}